// Round 2
// baseline (4074.939 us; speedup 1.0000x reference)
//
#include <hip/hip_runtime.h>
#include <hip/hip_fp16.h>

// SimpleHybridModel: conv1d(k=3,SAME,relu) -> SimpleRNN(16,tanh,last) -> dense(8,relu) -> dense(1)
// B=262144, L=20, F=7, C=H=16, D1=8. f32 in/out; x staged in LDS as f16.
//
// R2 changes vs R1:
//  - #pragma unroll 1 on the l-loop: R1's full unroll spilled ~2.7KB/thread to
//    scratch (FETCH 7.2GB, WRITE 718MB, VALUBusy 3.8%). Keep one iter live.
//  - per-thread x stride padded 280B -> 284B (71 dwords, gcd(71,32)=1 ->
//    2 lanes/bank on reads = conflict-free).

#define BLK 128           // threads per block == batch elements per block
#define LSEQ 20
#define NF 7
#define LF (LSEQ*NF)        // 140 floats per element
#define PADB 284            // padded bytes per element in LDS (142 halves)

// weight LDS layout offsets (floats)
#define W_CONV   0        // 336 = 3*7*16  [k][f][co]
#define W_CONVB  336      // 16
#define W_RNNW   352      // 256 [c][h]
#define W_RNNU   608      // 256 [j][h]
#define W_RNNB   864      // 16
#define W_D1W    880      // 128 [h][d]
#define W_D1B    1008     // 8
#define W_OUTW   1016     // 8
#define W_OUTB   1024     // 1

__global__ __launch_bounds__(BLK, 2) void hybrid_fwd(
    const float* __restrict__ x,
    const float* __restrict__ conv_w, const float* __restrict__ conv_b,
    const float* __restrict__ rnn_w,  const float* __restrict__ rnn_u,
    const float* __restrict__ rnn_b,
    const float* __restrict__ d1_w,   const float* __restrict__ d1_b,
    const float* __restrict__ out_w,  const float* __restrict__ out_b,
    float* __restrict__ out)
{
    __shared__ __half xs[BLK * (PADB / 2)];   // 36352 B, padded per-element rows
    __shared__ float  w[1032];                // 4128 B

    const int tid = threadIdx.x;
    const long blockBase = (long)blockIdx.x * (BLK * LF);

    // ---- stage x tile: contiguous float4 loads -> half2 -> LDS (padded) ----
    // float4 group g covers floats [4g..4g+3]; 35 groups per element (140/4).
    // element e = g/35, sub k = g%35 -> LDS byte 284*e + 8*k (4B-aligned).
    const float4* xsrc = (const float4*)(x + blockBase);
    char* xsb = (char*)xs;
    #pragma unroll
    for (int i = 0; i < LF / 4; ++i) {          // 35 iters
        int g = tid + i * BLK;
        float4 v = xsrc[g];
        int e = g / 35;
        int k = g - e * 35;
        __half2* dst = (__half2*)(xsb + e * PADB + k * 8);
        dst[0] = __floats2half2_rn(v.x, v.y);
        dst[1] = __floats2half2_rn(v.z, v.w);
    }
    // ---- stage weights ----
    for (int i = tid; i < 336; i += BLK) w[W_CONV  + i] = conv_w[i];
    for (int i = tid; i < 16;  i += BLK) w[W_CONVB + i] = conv_b[i];
    for (int i = tid; i < 256; i += BLK) w[W_RNNW  + i] = rnn_w[i];
    for (int i = tid; i < 256; i += BLK) w[W_RNNU  + i] = rnn_u[i];
    for (int i = tid; i < 16;  i += BLK) w[W_RNNB  + i] = rnn_b[i];
    for (int i = tid; i < 128; i += BLK) w[W_D1W   + i] = d1_w[i];
    for (int i = tid; i < 8;   i += BLK) { w[W_D1B + i] = d1_b[i]; w[W_OUTW + i] = out_w[i]; }
    if (tid == 0) w[W_OUTB] = out_b[0];
    __syncthreads();

    const __half* myx = (const __half*)(xsb + tid * PADB);

    float h[16];
    #pragma unroll
    for (int i = 0; i < 16; ++i) h[i] = 0.f;

    #pragma unroll 1           // CRITICAL: full unroll spills to scratch
    for (int l = 0; l < LSEQ; ++l) {
        // ---- conv1d (k=3, SAME) + bias ----
        float c[16];
        #pragma unroll
        for (int co = 0; co < 16; ++co) c[co] = w[W_CONVB + co];
        #pragma unroll
        for (int kk = 0; kk < 3; ++kk) {
            int ll = l + kk - 1;
            float m = (ll >= 0 && ll < LSEQ) ? 1.f : 0.f;   // branchless SAME padding
            int lc = min(max(ll, 0), LSEQ - 1);
            #pragma unroll
            for (int f = 0; f < NF; ++f) {
                float xv = m * __half2float(myx[lc * NF + f]);
                #pragma unroll
                for (int co = 0; co < 16; ++co)
                    c[co] = fmaf(xv, w[W_CONV + (kk * NF + f) * 16 + co], c[co]);
            }
        }
        // ---- s = relu(c) @ rnn_w + rnn_b + h @ rnn_u ----
        float s[16];
        #pragma unroll
        for (int hh = 0; hh < 16; ++hh) s[hh] = w[W_RNNB + hh];
        #pragma unroll
        for (int cc = 0; cc < 16; ++cc) {
            float r = fmaxf(c[cc], 0.f);
            #pragma unroll
            for (int hh = 0; hh < 16; ++hh)
                s[hh] = fmaf(r, w[W_RNNW + cc * 16 + hh], s[hh]);
        }
        #pragma unroll
        for (int jj = 0; jj < 16; ++jj) {
            float hv = h[jj];
            #pragma unroll
            for (int hh = 0; hh < 16; ++hh)
                s[hh] = fmaf(hv, w[W_RNNU + jj * 16 + hh], s[hh]);
        }
        // ---- h = tanh(s) via fast exp ----
        #pragma unroll
        for (int hh = 0; hh < 16; ++hh) {
            float e = __expf(2.f * s[hh]);
            h[hh] = 1.f - 2.f / (1.f + e);
        }
    }

    // ---- head: relu(h @ d1_w + d1_b) @ out_w + out_b ----
    float acc = w[W_OUTB];
    #pragma unroll
    for (int d = 0; d < 8; ++d) {
        float z = w[W_D1B + d];
        #pragma unroll
        for (int hh = 0; hh < 16; ++hh)
            z = fmaf(h[hh], w[W_D1W + hh * 8 + d], z);
        z = fmaxf(z, 0.f);
        acc = fmaf(z, w[W_OUTW + d], acc);
    }
    out[(long)blockIdx.x * BLK + tid] = acc;
}

extern "C" void kernel_launch(void* const* d_in, const int* in_sizes, int n_in,
                              void* d_out, int out_size, void* d_ws, size_t ws_size,
                              hipStream_t stream) {
    const float* x      = (const float*)d_in[0];
    const float* conv_w = (const float*)d_in[1];
    const float* conv_b = (const float*)d_in[2];
    const float* rnn_w  = (const float*)d_in[3];
    const float* rnn_u  = (const float*)d_in[4];
    const float* rnn_b  = (const float*)d_in[5];
    const float* d1_w   = (const float*)d_in[6];
    const float* d1_b   = (const float*)d_in[7];
    const float* out_w  = (const float*)d_in[8];
    const float* out_b  = (const float*)d_in[9];
    float* out = (float*)d_out;

    const int B = out_size;                 // 262144
    const int grid = B / BLK;               // 2048
    hybrid_fwd<<<grid, BLK, 0, stream>>>(x, conv_w, conv_b, rnn_w, rnn_u, rnn_b,
                                         d1_w, d1_b, out_w, out_b, out);
}

// Round 3
// 3724.260 us; speedup vs baseline: 1.0942x; 1.0942x over previous
//
#include <hip/hip_runtime.h>
#include <hip/hip_fp16.h>

// SimpleHybridModel: conv1d(k=3,SAME,relu) -> SimpleRNN(16,tanh,last) -> dense(8,relu) -> dense(1)
// B=262144, L=20, F=7, C=H=16, D1=8. f32 in/out; x staged in LDS as f16.
//
// R3 changes vs R2 (spill-kill):
//  - __launch_bounds__(128, 1): lift VGPR cap (was effectively 128 -> scratch
//    spill -> 7.9GB HBM traffic, 50x ideal). LDS caps occupancy at 4 blk/CU
//    regardless, so this costs nothing.
//  - staging loop #pragma unroll 4: R1/R2's full 35-deep unroll kept up to
//    140 VGPRs of float4 data in flight -> pressure. Bound it to 4.
//  - l-loop unroll 2: mild ILP without pressure.

#define BLK 128           // threads per block == batch elements per block
#define LSEQ 20
#define NF 7
#define LF (LSEQ*NF)        // 140 floats per element
#define PADB 284            // padded bytes per element in LDS (142 halves; 71 dwords, gcd(71,32)=1 -> 2-way = free)

// weight LDS layout offsets (floats)
#define W_CONV   0        // 336 = 3*7*16  [k][f][co]
#define W_CONVB  336      // 16
#define W_RNNW   352      // 256 [c][h]
#define W_RNNU   608      // 256 [j][h]
#define W_RNNB   864      // 16
#define W_D1W    880      // 128 [h][d]
#define W_D1B    1008     // 8
#define W_OUTW   1016     // 8
#define W_OUTB   1024     // 1

__global__ __launch_bounds__(BLK, 1) void hybrid_fwd(
    const float* __restrict__ x,
    const float* __restrict__ conv_w, const float* __restrict__ conv_b,
    const float* __restrict__ rnn_w,  const float* __restrict__ rnn_u,
    const float* __restrict__ rnn_b,
    const float* __restrict__ d1_w,   const float* __restrict__ d1_b,
    const float* __restrict__ out_w,  const float* __restrict__ out_b,
    float* __restrict__ out)
{
    __shared__ __half xs[BLK * (PADB / 2)];   // 36352 B, padded per-element rows
    __shared__ float  w[1032];                // 4128 B

    const int tid = threadIdx.x;
    const long blockBase = (long)blockIdx.x * (BLK * LF);

    // ---- stage x tile: contiguous float4 loads -> half2 -> LDS (padded) ----
    // float4 group g covers floats [4g..4g+3]; 35 groups per element (140/4).
    // element e = g/35, sub k = g%35 -> LDS byte 284*e + 8*k (4B-aligned).
    const float4* xsrc = (const float4*)(x + blockBase);
    char* xsb = (char*)xs;
    #pragma unroll 4
    for (int i = 0; i < LF / 4; ++i) {          // 35 iters, bounded in-flight regs
        int g = tid + i * BLK;
        float4 v = xsrc[g];
        int e = g / 35;
        int k = g - e * 35;
        __half2* dst = (__half2*)(xsb + e * PADB + k * 8);
        dst[0] = __floats2half2_rn(v.x, v.y);
        dst[1] = __floats2half2_rn(v.z, v.w);
    }
    // ---- stage weights ----
    for (int i = tid; i < 336; i += BLK) w[W_CONV  + i] = conv_w[i];
    for (int i = tid; i < 16;  i += BLK) w[W_CONVB + i] = conv_b[i];
    for (int i = tid; i < 256; i += BLK) w[W_RNNW  + i] = rnn_w[i];
    for (int i = tid; i < 256; i += BLK) w[W_RNNU  + i] = rnn_u[i];
    for (int i = tid; i < 16;  i += BLK) w[W_RNNB  + i] = rnn_b[i];
    for (int i = tid; i < 128; i += BLK) w[W_D1W   + i] = d1_w[i];
    for (int i = tid; i < 8;   i += BLK) { w[W_D1B + i] = d1_b[i]; w[W_OUTW + i] = out_w[i]; }
    if (tid == 0) w[W_OUTB] = out_b[0];
    __syncthreads();

    const __half* myx = (const __half*)(xsb + tid * PADB);

    float h[16];
    #pragma unroll
    for (int i = 0; i < 16; ++i) h[i] = 0.f;

    #pragma unroll 2
    for (int l = 0; l < LSEQ; ++l) {
        // ---- conv1d (k=3, SAME) + bias ----
        float c[16];
        #pragma unroll
        for (int co = 0; co < 16; ++co) c[co] = w[W_CONVB + co];
        #pragma unroll
        for (int kk = 0; kk < 3; ++kk) {
            int ll = l + kk - 1;
            float m = (ll >= 0 && ll < LSEQ) ? 1.f : 0.f;   // branchless SAME padding
            int lc = min(max(ll, 0), LSEQ - 1);
            #pragma unroll
            for (int f = 0; f < NF; ++f) {
                float xv = m * __half2float(myx[lc * NF + f]);
                #pragma unroll
                for (int co = 0; co < 16; ++co)
                    c[co] = fmaf(xv, w[W_CONV + (kk * NF + f) * 16 + co], c[co]);
            }
        }
        // ---- s = relu(c) @ rnn_w + rnn_b + h @ rnn_u ----
        float s[16];
        #pragma unroll
        for (int hh = 0; hh < 16; ++hh) s[hh] = w[W_RNNB + hh];
        #pragma unroll
        for (int cc = 0; cc < 16; ++cc) {
            float r = fmaxf(c[cc], 0.f);
            #pragma unroll
            for (int hh = 0; hh < 16; ++hh)
                s[hh] = fmaf(r, w[W_RNNW + cc * 16 + hh], s[hh]);
        }
        #pragma unroll
        for (int jj = 0; jj < 16; ++jj) {
            float hv = h[jj];
            #pragma unroll
            for (int hh = 0; hh < 16; ++hh)
                s[hh] = fmaf(hv, w[W_RNNU + jj * 16 + hh], s[hh]);
        }
        // ---- h = tanh(s) via fast exp ----
        #pragma unroll
        for (int hh = 0; hh < 16; ++hh) {
            float e = __expf(2.f * s[hh]);
            h[hh] = 1.f - 2.f / (1.f + e);
        }
    }

    // ---- head: relu(h @ d1_w + d1_b) @ out_w + out_b ----
    float acc = w[W_OUTB];
    #pragma unroll
    for (int d = 0; d < 8; ++d) {
        float z = w[W_D1B + d];
        #pragma unroll
        for (int hh = 0; hh < 16; ++hh)
            z = fmaf(h[hh], w[W_D1W + hh * 8 + d], z);
        z = fmaxf(z, 0.f);
        acc = fmaf(z, w[W_OUTW + d], acc);
    }
    out[(long)blockIdx.x * BLK + tid] = acc;
}

extern "C" void kernel_launch(void* const* d_in, const int* in_sizes, int n_in,
                              void* d_out, int out_size, void* d_ws, size_t ws_size,
                              hipStream_t stream) {
    const float* x      = (const float*)d_in[0];
    const float* conv_w = (const float*)d_in[1];
    const float* conv_b = (const float*)d_in[2];
    const float* rnn_w  = (const float*)d_in[3];
    const float* rnn_u  = (const float*)d_in[4];
    const float* rnn_b  = (const float*)d_in[5];
    const float* d1_w   = (const float*)d_in[6];
    const float* d1_b   = (const float*)d_in[7];
    const float* out_w  = (const float*)d_in[8];
    const float* out_b  = (const float*)d_in[9];
    float* out = (float*)d_out;

    const int B = out_size;                 // 262144
    const int grid = B / BLK;               // 2048
    hybrid_fwd<<<grid, BLK, 0, stream>>>(x, conv_w, conv_b, rnn_w, rnn_u, rnn_b,
                                         d1_w, d1_b, out_w, out_b, out);
}

// Round 4
// 758.953 us; speedup vs baseline: 5.3692x; 4.9071x over previous
//
#include <hip/hip_runtime.h>

// SimpleHybridModel: conv1d(k=3,SAME,relu) -> SimpleRNN(16,tanh,last) -> dense(8,relu) -> dense(1)
// B=262144, L=20, F=7, C=H=16, D1=8. All f32.
//
// R4 redesign: R1-R3 all showed ~7GB HBM traffic (50x ideal) + VALUBusy 4%
// regardless of unroll/launch_bounds/VGPR budget. Eliminate every suspect:
//  - NO x LDS tile: rolling 3-row register window, per-iter prefetch of one
//    7-float row per thread from global (dense rows -> line-efficient, L2-cached).
//  - NO weight LDS: weights read with wave-uniform, compile-time-constant
//    offsets from __restrict__ global pointers -> backend emits s_load_dwordx16
//    (scalar cache, scalar pipe; 16 consecutive outputs per load).
//  - NO LDS at all, no __syncthreads, rolled l-loop with explicit register
//    rotation (static indexing, small body, no spill pressure).
//  - __launch_bounds__(256,4): cap 128 VGPR -> 16 waves/CU.

#define BLK 256
#define LSEQ 20
#define NF 7

__global__ __launch_bounds__(BLK, 4) void hybrid_fwd(
    const float* __restrict__ x,
    const float* __restrict__ conv_w, const float* __restrict__ conv_b,
    const float* __restrict__ rnn_w,  const float* __restrict__ rnn_u,
    const float* __restrict__ rnn_b,
    const float* __restrict__ d1_w,   const float* __restrict__ d1_b,
    const float* __restrict__ out_w,  const float* __restrict__ out_b,
    float* __restrict__ out)
{
    const long e = (long)blockIdx.x * BLK + threadIdx.x;
    const float* xe = x + e * (LSEQ * NF);

    // rolling window: r0=row l-1, r1=row l, r2=row l+1
    float r0[NF], r1[NF], r2[NF];
    #pragma unroll
    for (int f = 0; f < NF; ++f) {
        r0[f] = 0.f;                 // masked at l=0, but keep finite
        r1[f] = xe[f];               // row 0
        r2[f] = xe[NF + f];          // row 1
    }

    float h[16];
    #pragma unroll
    for (int i = 0; i < 16; ++i) h[i] = 0.f;

    #pragma unroll 1
    for (int l = 0; l < LSEQ; ++l) {
        // prefetch row l+2 (clamped; clamped dup is masked when consumed)
        float rn[NF];
        {
            int lp = l + 2; if (lp > LSEQ - 1) lp = LSEQ - 1;
            const float* rp = xe + NF * lp;
            #pragma unroll
            for (int f = 0; f < NF; ++f) rn[f] = rp[f];
        }
        const float mP = (l >= 1)        ? 1.f : 0.f;   // row l-1 validity
        const float mN = (l <= LSEQ - 2) ? 1.f : 0.f;   // row l+1 validity

        // ---- conv1d (k=3, SAME) + bias; weights: uniform const-offset loads ----
        float c[16];
        #pragma unroll
        for (int co = 0; co < 16; ++co) c[co] = conv_b[co];
        #pragma unroll
        for (int f = 0; f < NF; ++f) {
            const float x0 = mP * r0[f];
            const float x1 = r1[f];
            const float x2 = mN * r2[f];
            #pragma unroll
            for (int co = 0; co < 16; ++co) {
                c[co] = fmaf(x0, conv_w[(0 * NF + f) * 16 + co], c[co]);
                c[co] = fmaf(x1, conv_w[(1 * NF + f) * 16 + co], c[co]);
                c[co] = fmaf(x2, conv_w[(2 * NF + f) * 16 + co], c[co]);
            }
        }
        // ---- s = relu(c) @ rnn_w + rnn_b + h @ rnn_u ----
        float s[16];
        #pragma unroll
        for (int hh = 0; hh < 16; ++hh) s[hh] = rnn_b[hh];
        #pragma unroll
        for (int cc = 0; cc < 16; ++cc) {
            const float r = fmaxf(c[cc], 0.f);
            #pragma unroll
            for (int hh = 0; hh < 16; ++hh)
                s[hh] = fmaf(r, rnn_w[cc * 16 + hh], s[hh]);
        }
        #pragma unroll
        for (int jj = 0; jj < 16; ++jj) {
            const float hv = h[jj];
            #pragma unroll
            for (int hh = 0; hh < 16; ++hh)
                s[hh] = fmaf(hv, rnn_u[jj * 16 + hh], s[hh]);
        }
        // ---- h = tanh(s) ----
        #pragma unroll
        for (int hh = 0; hh < 16; ++hh) {
            const float ee = __expf(2.f * s[hh]);
            h[hh] = 1.f - 2.f / (1.f + ee);
        }
        // ---- rotate window ----
        #pragma unroll
        for (int f = 0; f < NF; ++f) { r0[f] = r1[f]; r1[f] = r2[f]; r2[f] = rn[f]; }
    }

    // ---- head: relu(h @ d1_w + d1_b) @ out_w + out_b ----
    float acc = out_b[0];
    #pragma unroll
    for (int d = 0; d < 8; ++d) {
        float z = d1_b[d];
        #pragma unroll
        for (int hh = 0; hh < 16; ++hh)
            z = fmaf(h[hh], d1_w[hh * 8 + d], z);
        z = fmaxf(z, 0.f);
        acc = fmaf(z, out_w[d], acc);
    }
    out[e] = acc;
}

extern "C" void kernel_launch(void* const* d_in, const int* in_sizes, int n_in,
                              void* d_out, int out_size, void* d_ws, size_t ws_size,
                              hipStream_t stream) {
    const float* x      = (const float*)d_in[0];
    const float* conv_w = (const float*)d_in[1];
    const float* conv_b = (const float*)d_in[2];
    const float* rnn_w  = (const float*)d_in[3];
    const float* rnn_u  = (const float*)d_in[4];
    const float* rnn_b  = (const float*)d_in[5];
    const float* d1_w   = (const float*)d_in[6];
    const float* d1_b   = (const float*)d_in[7];
    const float* out_w  = (const float*)d_in[8];
    const float* out_b  = (const float*)d_in[9];
    float* out = (float*)d_out;

    const int B = out_size;                 // 262144
    const int grid = B / BLK;               // 1024
    hybrid_fwd<<<grid, BLK, 0, stream>>>(x, conv_w, conv_b, rnn_w, rnn_u, rnn_b,
                                         d1_w, d1_b, out_w, out_b, out);
}

// Round 5
// 68.140 us; speedup vs baseline: 59.8027x; 11.1382x over previous
//
#include <hip/hip_runtime.h>

// SimpleHybridModel via MFMA, all-transposed chaining (no lane shuffles):
//  conv1d(k=3,SAME,relu) -> SimpleRNN(16,tanh) -> dense(8,relu) -> dense(1)
// Per wave: 16 batch elements. D-layout of each MFMA == B-layout of the next.
// Weights live in per-lane A-fragments (loaded once). x staged in LDS (f32,
// row stride 157 dwords -> exact 2-way banks = free; zero-padded SAME windows).

#define BLK 256   // 4 waves; each wave owns 16 batch elements
#define LSEQ 20
#define NF 7
#define ROWF 157          // floats per LDS row: 7 zero | 140 x | 10 zero
#define WAVEF (ROWF*16+8) // +8 guard dwords (read by g=3 garbage reads; zeroed)

typedef _Float16 f16;
typedef _Float16 f16x4 __attribute__((ext_vector_type(4)));
typedef _Float16 f16x8 __attribute__((ext_vector_type(8)));
typedef float    f32x4 __attribute__((ext_vector_type(4)));

__global__ __launch_bounds__(BLK, 4) void hybrid_fwd(
    const float* __restrict__ x,
    const float* __restrict__ conv_w, const float* __restrict__ conv_b,
    const float* __restrict__ rnn_w,  const float* __restrict__ rnn_u,
    const float* __restrict__ rnn_b,
    const float* __restrict__ d1_w,   const float* __restrict__ d1_b,
    const float* __restrict__ out_w,  const float* __restrict__ out_b,
    float* __restrict__ out)
{
    __shared__ float xs[4][WAVEF];   // 4 waves * 2520 dwords = 40320 B

    const int tid  = threadIdx.x;
    const int wave = tid >> 6, lane = tid & 63;
    const int b16  = lane & 15, g = lane >> 4;
    const long BE  = (long)blockIdx.x * 64;          // block's first batch elem

    // ---- stage x: 64 elems * 140 f32 contiguous -> LDS rows (padded) ----
    const float4* xsrc = (const float4*)(x + BE * (LSEQ * NF));
    #pragma unroll
    for (int i = 0; i < 9; ++i) {
        int idx = tid + i * BLK;                     // float4 index, 2240 total
        if (idx < 2240) {
            float4 v = xsrc[idx];
            int e  = idx / 35;                       // elem in block 0..63
            int f4 = idx - e * 35;
            float* dst = &xs[e >> 4][ROWF * (e & 15) + 7 + f4 * 4];
            dst[0] = v.x; dst[1] = v.y; dst[2] = v.z; dst[3] = v.w;
        }
    }
    // ---- zero pads: per row floats [0..6] and [147..156], + 8 guard/wave ----
    #pragma unroll
    for (int i = 0; i < 5; ++i) {
        int j = tid + i * BLK;                       // 1120 total
        if (j < 1120) {
            int w_ = j / 280, r_ = j - w_ * 280, off;
            if (r_ < 112)      off = ROWF * (r_ / 7) + (r_ % 7);
            else if (r_ < 272) { int q = r_ - 112; off = ROWF * (q / 10) + 147 + (q % 10); }
            else               off = ROWF * 16 + (r_ - 272);
            xs[w_][off] = 0.f;
        }
    }
    __syncthreads();

    // ---- weight fragments (loaded once, register-resident) ----
    // A1[m=co=b16, k=8g+t] = conv_w[k][co], zero for k>=21 (annihilates garbage B)
    f16x8 A1;
    #pragma unroll
    for (int t = 0; t < 8; ++t) {
        int k = 8 * g + t;
        float wv = conv_w[min(k, 20) * 16 + b16];    // clamped: always in-bounds
        A1[t] = (f16)(k < 21 ? wv : 0.f);
    }
    // A2[m=j=b16, k=c=4g+t] = rnn_w[c][j];  AU[m=j, k=i] = rnn_u[i][j]
    f16x4 A2, AU;
    #pragma unroll
    for (int t = 0; t < 4; ++t) {
        A2[t] = (f16)rnn_w[(4 * g + t) * 16 + b16];
        AU[t] = (f16)rnn_u[(4 * g + t) * 16 + b16];
    }
    f32x4 cb, rb;                                    // bias in D-layout rows
    #pragma unroll
    for (int r = 0; r < 4; ++r) { cb[r] = conv_b[4 * g + r]; rb[r] = rnn_b[4 * g + r]; }

    // per-lane LDS base; per-l reads are base + immediate offsets (7l+j)
    const float* xrow = &xs[wave][ROWF * b16 + 8 * g];

    f16x4 H;                     // H^T fragment: H[b=b16, i=4g+t]
    #pragma unroll
    for (int r = 0; r < 4; ++r) H[r] = (f16)0.f;
    float hf[4];                 // f32 copy of final h for the head

    #pragma unroll 2
    for (int l = 0; l < LSEQ; ++l) {
        // B1[k=8g+j, n=b16] = xflat[b16, 7(l-1)+k]  (zero-padded window)
        f16x8 B1;
        #pragma unroll
        for (int j = 0; j < 8; ++j) B1[j] = (f16)xrow[7 * l + j];
        f32x4 a1 = cb;
        a1 = __builtin_amdgcn_mfma_f32_16x16x32_f16(A1, B1, a1, 0, 0, 0);
        // relu -> B2 (D1 layout == B layout, no shuffle)
        f16x4 B2;
        #pragma unroll
        for (int r = 0; r < 4; ++r) B2[r] = (f16)fmaxf(a1[r], 0.f);
        f32x4 a2 = rb;
        a2 = __builtin_amdgcn_mfma_f32_16x16x16f16(A2, B2, a2, 0, 0, 0);
        a2 = __builtin_amdgcn_mfma_f32_16x16x16f16(AU, H,  a2, 0, 0, 0);
        // tanh -> next H fragment (D2 layout == B layout)
        #pragma unroll
        for (int r = 0; r < 4; ++r) {
            float e2 = __expf(2.f * a2[r]);
            hf[r] = 1.f - 2.f / (1.f + e2);
            H[r] = (f16)hf[r];
        }
    }

    // ---- head: p[d] = sum_j h[b,j]*d1_w[j][d], j split 4 per lane-group ----
    float p[8];
    #pragma unroll
    for (int d = 0; d < 8; ++d) p[d] = 0.f;
    #pragma unroll
    for (int t = 0; t < 4; ++t) {
        float hv = hf[t];
        #pragma unroll
        for (int d = 0; d < 8; ++d)
            p[d] = fmaf(hv, d1_w[(4 * g + t) * 8 + d], p[d]);
    }
    #pragma unroll
    for (int d = 0; d < 8; ++d) {
        p[d] += __shfl_xor(p[d], 16);
        p[d] += __shfl_xor(p[d], 32);
    }
    if (lane < 16) {
        float a = out_b[0];
        #pragma unroll
        for (int d = 0; d < 8; ++d) {
            float z = fmaxf(p[d] + d1_b[d], 0.f);
            a = fmaf(z, out_w[d], a);
        }
        out[BE + wave * 16 + lane] = a;
    }
}

extern "C" void kernel_launch(void* const* d_in, const int* in_sizes, int n_in,
                              void* d_out, int out_size, void* d_ws, size_t ws_size,
                              hipStream_t stream) {
    const float* x      = (const float*)d_in[0];
    const float* conv_w = (const float*)d_in[1];
    const float* conv_b = (const float*)d_in[2];
    const float* rnn_w  = (const float*)d_in[3];
    const float* rnn_u  = (const float*)d_in[4];
    const float* rnn_b  = (const float*)d_in[5];
    const float* d1_w   = (const float*)d_in[6];
    const float* d1_b   = (const float*)d_in[7];
    const float* out_w  = (const float*)d_in[8];
    const float* out_b  = (const float*)d_in[9];
    float* out = (float*)d_out;

    const int B = out_size;                 // 262144
    const int grid = B / 64;                // 4096 blocks (4 waves * 16 elems)
    hybrid_fwd<<<grid, BLK, 0, stream>>>(x, conv_w, conv_b, rnn_w, rnn_u, rnn_b,
                                         d1_w, d1_b, out_w, out_b, out);
}

// Round 6
// 54.874 us; speedup vs baseline: 74.2605x; 1.2418x over previous
//
#include <hip/hip_runtime.h>

// SimpleHybridModel via MFMA, all-transposed chaining (no lane shuffles):
//  conv1d(k=3,SAME,relu) -> SimpleRNN(16,tanh) -> dense(8,relu) -> dense(1)
// Per wave: 16 batch elements. D-layout of each MFMA == B-layout of the next.
// Weights live in per-lane A-fragments (loaded once). x staged in LDS (f32,
// row stride 157 dwords, odd -> loop reads exact 2-way banks = free).
//
// R6 changes vs R5:
//  - tanh: IEEE division replaced by v_rcp_f32 (fmaf(-2, rcp(1+e), 1)):
//    kills ~36 VALU instr/iter (div_scale/div_fmas/div_fixup sequence).
//  - staging: scalar-coalesced (lane-stride-1 on BOTH global read and LDS
//    write) -> conflict-free; R5's float4 staging wrote lane-stride-16B at
//    odd dword base = 4-8-way bank conflicts (8.0M cycles/dispatch).
//  - pad-zeroing trimmed to the consumed range (front 7 + back 7 per row);
//    offsets >=147+7 and the guard are only read where A1[k>=21]==0.

#define BLK 256   // 4 waves; each wave owns 16 batch elements
#define LSEQ 20
#define NF 7
#define ROWF 157          // dwords per LDS row: 7 zero | 140 x | 10 slack
#define WAVEF (ROWF*16+8) // +8 guard dwords (read only by k>=21 lanes; A=0)

typedef _Float16 f16;
typedef _Float16 f16x4 __attribute__((ext_vector_type(4)));
typedef _Float16 f16x8 __attribute__((ext_vector_type(8)));
typedef float    f32x4 __attribute__((ext_vector_type(4)));

__global__ __launch_bounds__(BLK, 4) void hybrid_fwd(
    const float* __restrict__ x,
    const float* __restrict__ conv_w, const float* __restrict__ conv_b,
    const float* __restrict__ rnn_w,  const float* __restrict__ rnn_u,
    const float* __restrict__ rnn_b,
    const float* __restrict__ d1_w,   const float* __restrict__ d1_b,
    const float* __restrict__ out_w,  const float* __restrict__ out_b,
    float* __restrict__ out)
{
    __shared__ float xs[4 * WAVEF];   // 40320 B

    const int tid  = threadIdx.x;
    const int wave = tid >> 6, lane = tid & 63;
    const int b16  = lane & 15, g = lane >> 4;
    const long BE  = (long)blockIdx.x * 64;          // block's first batch elem

    // ---- zero the consumed pad dwords: per row front [0..6], back [147..153]
    #pragma unroll
    for (int k = 0; k < 4; ++k) {
        int t = tid + k * BLK;                       // need 896
        if (t < 896) {
            int half = (t >= 448) ? 1 : 0;
            int q = t - half * 448;                  // 0..447
            int row = q / 7, c = q - row * 7;        // row 0..63
            xs[(row >> 4) * WAVEF + ROWF * (row & 15) + (half ? 147 + c : c)] = 0.f;
        }
    }

    // ---- stage x: scalar-coalesced, lane-stride-1 global AND LDS ----
    // flat i in [0,8960): e = i/140 (elem 0..63), r = i%140
    const float* xg = x + BE * (LSEQ * NF);
    #pragma unroll
    for (int k = 0; k < 35; ++k) {
        int i = tid + k * BLK;
        float v = xg[i];
        int e = i / 140;
        int r = i - e * 140;
        xs[(e >> 4) * WAVEF + ROWF * (e & 15) + 7 + r] = v;
    }
    __syncthreads();

    // ---- weight fragments (loaded once, register-resident) ----
    // A1[m=co=b16, k=8g+t] = conv_w[k][co], zero for k>=21 (annihilates garbage B)
    f16x8 A1;
    #pragma unroll
    for (int t = 0; t < 8; ++t) {
        int k = 8 * g + t;
        float wv = conv_w[min(k, 20) * 16 + b16];    // clamped: always in-bounds
        A1[t] = (f16)(k < 21 ? wv : 0.f);
    }
    // A2[m=j=b16, k=c=4g+t] = rnn_w[c][j];  AU[m=j, k=i] = rnn_u[i][j]
    f16x4 A2, AU;
    #pragma unroll
    for (int t = 0; t < 4; ++t) {
        A2[t] = (f16)rnn_w[(4 * g + t) * 16 + b16];
        AU[t] = (f16)rnn_u[(4 * g + t) * 16 + b16];
    }
    f32x4 cb, rb;                                    // bias in D-layout rows
    #pragma unroll
    for (int r = 0; r < 4; ++r) { cb[r] = conv_b[4 * g + r]; rb[r] = rnn_b[4 * g + r]; }

    // per-lane LDS base; per-l reads are base + immediate offsets
    const float* xrow = &xs[wave * WAVEF + ROWF * b16 + 8 * g];

    f16x4 H;                     // H^T fragment: H[b=b16, i=4g+t]
    #pragma unroll
    for (int r = 0; r < 4; ++r) H[r] = (f16)0.f;
    float hf[4];                 // f32 copy of final h for the head

    #pragma unroll 2
    for (int l = 0; l < LSEQ; ++l) {
        // B1[k=8g+j, n=b16] = xpad[b16, 7(l-1)+k]  (zero-padded window)
        f16x8 B1;
        #pragma unroll
        for (int j = 0; j < 8; ++j) B1[j] = (f16)xrow[7 * l + j];
        f32x4 a1 = cb;
        a1 = __builtin_amdgcn_mfma_f32_16x16x32_f16(A1, B1, a1, 0, 0, 0);
        // relu -> B2 (D1 layout == B layout, no shuffle)
        f16x4 B2;
        #pragma unroll
        for (int r = 0; r < 4; ++r) B2[r] = (f16)fmaxf(a1[r], 0.f);
        f32x4 a2 = rb;
        a2 = __builtin_amdgcn_mfma_f32_16x16x16f16(A2, B2, a2, 0, 0, 0);
        a2 = __builtin_amdgcn_mfma_f32_16x16x16f16(AU, H,  a2, 0, 0, 0);
        // tanh via exp + v_rcp (no IEEE div): h = 1 - 2*rcp(1+e)
        #pragma unroll
        for (int r = 0; r < 4; ++r) {
            float e2 = __expf(2.f * a2[r]);
            float t  = __builtin_amdgcn_rcpf(1.f + e2);
            hf[r] = fmaf(-2.f, t, 1.f);
            H[r] = (f16)hf[r];
        }
    }

    // ---- head: p[d] = sum_j h[b,j]*d1_w[j][d], j split 4 per lane-group ----
    float p[8];
    #pragma unroll
    for (int d = 0; d < 8; ++d) p[d] = 0.f;
    #pragma unroll
    for (int t = 0; t < 4; ++t) {
        float hv = hf[t];
        #pragma unroll
        for (int d = 0; d < 8; ++d)
            p[d] = fmaf(hv, d1_w[(4 * g + t) * 8 + d], p[d]);
    }
    #pragma unroll
    for (int d = 0; d < 8; ++d) {
        p[d] += __shfl_xor(p[d], 16);
        p[d] += __shfl_xor(p[d], 32);
    }
    if (lane < 16) {
        float a = out_b[0];
        #pragma unroll
        for (int d = 0; d < 8; ++d) {
            float z = fmaxf(p[d] + d1_b[d], 0.f);
            a = fmaf(z, out_w[d], a);
        }
        out[BE + wave * 16 + lane] = a;
    }
}

extern "C" void kernel_launch(void* const* d_in, const int* in_sizes, int n_in,
                              void* d_out, int out_size, void* d_ws, size_t ws_size,
                              hipStream_t stream) {
    const float* x      = (const float*)d_in[0];
    const float* conv_w = (const float*)d_in[1];
    const float* conv_b = (const float*)d_in[2];
    const float* rnn_w  = (const float*)d_in[3];
    const float* rnn_u  = (const float*)d_in[4];
    const float* rnn_b  = (const float*)d_in[5];
    const float* d1_w   = (const float*)d_in[6];
    const float* d1_b   = (const float*)d_in[7];
    const float* out_w  = (const float*)d_in[8];
    const float* out_b  = (const float*)d_in[9];
    float* out = (float*)d_out;

    const int B = out_size;                 // 262144
    const int grid = B / 64;                // 4096 blocks (4 waves * 16 elems)
    hybrid_fwd<<<grid, BLK, 0, stream>>>(x, conv_w, conv_b, rnn_w, rnn_u, rnn_b,
                                         d1_w, d1_b, out_w, out_b, out);
}

// Round 7
// 52.206 us; speedup vs baseline: 78.0543x; 1.0511x over previous
//
#include <hip/hip_runtime.h>

// SimpleHybridModel via MFMA, all-transposed chaining (no lane shuffles):
//  conv1d(k=3,SAME,relu) -> SimpleRNN(16,tanh) -> dense(8,relu) -> dense(1)
// Per wave: 16 batch elements. D-layout of each MFMA == B-layout of the next.
//
// R7 changes vs R6 (occupancy + loop-VALU):
//  - x staged in LDS as f16 (row = 166 halves = 83 dwords: 8 zero | 140 x |
//    18 zero): LDS 40.4KB -> 21.25KB, 3 -> 6+ blocks/CU (12 -> 24+ waves/CU).
//    R5/R6 were latency-bound on the serial iter chain at 3 waves/SIMD.
//  - per-iter f32->f16 cvts (8) move to staging (paid once, RTN kept).
//  - window start 1+7l+8g alternates parity with l: #pragma unroll 4 makes
//    parity compile-time; even-start iters = 4 dword LDS reads, odd-start =
//    5 dword reads + 4 v_alignbit. Row stride 83 dwords (83 mod 32 = 19,
//    gcd 1) -> worst 2-way banks = free.

#define BLK 256   // 4 waves; each wave owns 16 batch elements
#define LSEQ 20
#define ROWD 83           // dwords per LDS row (166 halves)

typedef _Float16 f16;
typedef _Float16 f16x4 __attribute__((ext_vector_type(4)));
typedef _Float16 f16x8 __attribute__((ext_vector_type(8)));
typedef float    f32x4 __attribute__((ext_vector_type(4)));

union U4 { uint u[4]; f16x8 v; };

__global__ __launch_bounds__(BLK, 6) void hybrid_fwd(
    const float* __restrict__ x,
    const float* __restrict__ conv_w, const float* __restrict__ conv_b,
    const float* __restrict__ rnn_w,  const float* __restrict__ rnn_u,
    const float* __restrict__ rnn_b,
    const float* __restrict__ d1_w,   const float* __restrict__ d1_b,
    const float* __restrict__ out_w,  const float* __restrict__ out_b,
    float* __restrict__ out)
{
    __shared__ uint xs[64 * ROWD];   // 21248 B

    const int tid  = threadIdx.x;
    const int wave = tid >> 6, lane = tid & 63;
    const int b16  = lane & 15, g = lane >> 4;
    const long BE  = (long)blockIdx.x * 64;          // block's first batch elem

    // ---- zero pad dwords: per row front [0..3], tail [74..82] (13 dwords) ----
    #pragma unroll
    for (int k = 0; k < 4; ++k) {
        int t = tid + k * BLK;                       // need 64*13 = 832
        if (t < 832) {
            int row = t / 13, wh = t - row * 13;
            xs[row * ROWD + (wh < 4 ? wh : 70 + wh)] = 0u;
        }
    }
    // ---- stage x: f32 pairs -> f16 pair -> one dword. halves [8..147]=xflat ----
    // pair p: e = p/70, q = p%70 -> global floats [140e+2q, +1], LDS dword 83e+4+q
    const float* xg = x + BE * 140;
    #pragma unroll
    for (int k = 0; k < 18; ++k) {
        int p = tid + k * BLK;
        if (p < 4480) {
            int e = p / 70, q = p - e * 70;
            float2 v = *(const float2*)(xg + e * 140 + 2 * q);
            f16 lo = (f16)v.x, hi = (f16)v.y;
            uint d = (uint)__builtin_bit_cast(unsigned short, lo) |
                     ((uint)__builtin_bit_cast(unsigned short, hi) << 16);
            xs[e * ROWD + 4 + q] = d;
        }
    }
    __syncthreads();

    // ---- weight fragments (loaded once, register-resident) ----
    // A1[m=co=b16, k=8g+t] = conv_w[k][co], zero for k>=21 (tail zeros in LDS
    // keep garbage-B finite; zero A annihilates it)
    f16x8 A1;
    #pragma unroll
    for (int t = 0; t < 8; ++t) {
        int k = 8 * g + t;
        float wv = conv_w[min(k, 20) * 16 + b16];
        A1[t] = (f16)(k < 21 ? wv : 0.f);
    }
    f16x4 A2, AU;
    #pragma unroll
    for (int t = 0; t < 4; ++t) {
        A2[t] = (f16)rnn_w[(4 * g + t) * 16 + b16];
        AU[t] = (f16)rnn_u[(4 * g + t) * 16 + b16];
    }
    f32x4 cb, rb;
    #pragma unroll
    for (int r = 0; r < 4; ++r) { cb[r] = conv_b[4 * g + r]; rb[r] = rnn_b[4 * g + r]; }

    // per-lane row base (dwords); per-l window = halves [1+7l+8g .. +7]
    const uint* rowp = &xs[(wave * 16 + b16) * ROWD];
    const int gh = 8 * g;                            // half offset of this group

    f16x4 H;
    #pragma unroll
    for (int r = 0; r < 4; ++r) H[r] = (f16)0.f;
    float hf[4];

    #pragma unroll 4
    for (int l = 0; l < LSEQ; ++l) {
        const int H0 = 1 + 7 * l + gh;               // window start (halves)
        U4 B1;
        if ((H0 & 1) == 0) {                         // even: 4 aligned dwords
            const int D = H0 >> 1;
            #pragma unroll
            for (int i = 0; i < 4; ++i) B1.u[i] = rowp[D + i];
        } else {                                     // odd: 5 dwords + alignbit
            const int D = (H0 - 1) >> 1;
            uint u[5];
            #pragma unroll
            for (int i = 0; i < 5; ++i) u[i] = rowp[D + i];
            #pragma unroll
            for (int i = 0; i < 4; ++i)
                B1.u[i] = __builtin_amdgcn_alignbit(u[i + 1], u[i], 16);
        }
        f32x4 a1 = cb;
        a1 = __builtin_amdgcn_mfma_f32_16x16x32_f16(A1, B1.v, a1, 0, 0, 0);
        // relu -> B2 (D layout == B layout, no shuffle); RTN cvt
        f16x4 B2;
        #pragma unroll
        for (int r = 0; r < 4; ++r) B2[r] = (f16)fmaxf(a1[r], 0.f);
        f32x4 a2 = rb;
        a2 = __builtin_amdgcn_mfma_f32_16x16x16f16(A2, B2, a2, 0, 0, 0);
        a2 = __builtin_amdgcn_mfma_f32_16x16x16f16(AU, H,  a2, 0, 0, 0);
        // tanh via exp + v_rcp: h = 1 - 2*rcp(1+e)
        #pragma unroll
        for (int r = 0; r < 4; ++r) {
            float e2 = __expf(2.f * a2[r]);
            float t  = __builtin_amdgcn_rcpf(1.f + e2);
            hf[r] = fmaf(-2.f, t, 1.f);
            H[r] = (f16)hf[r];
        }
    }

    // ---- head: p[d] = sum_j h[b,j]*d1_w[j][d], j split 4 per lane-group ----
    float p[8];
    #pragma unroll
    for (int d = 0; d < 8; ++d) p[d] = 0.f;
    #pragma unroll
    for (int t = 0; t < 4; ++t) {
        float hv = hf[t];
        #pragma unroll
        for (int d = 0; d < 8; ++d)
            p[d] = fmaf(hv, d1_w[(4 * g + t) * 8 + d], p[d]);
    }
    #pragma unroll
    for (int d = 0; d < 8; ++d) {
        p[d] += __shfl_xor(p[d], 16);
        p[d] += __shfl_xor(p[d], 32);
    }
    if (lane < 16) {
        float a = out_b[0];
        #pragma unroll
        for (int d = 0; d < 8; ++d) {
            float z = fmaxf(p[d] + d1_b[d], 0.f);
            a = fmaf(z, out_w[d], a);
        }
        out[BE + wave * 16 + lane] = a;
    }
}

extern "C" void kernel_launch(void* const* d_in, const int* in_sizes, int n_in,
                              void* d_out, int out_size, void* d_ws, size_t ws_size,
                              hipStream_t stream) {
    const float* x      = (const float*)d_in[0];
    const float* conv_w = (const float*)d_in[1];
    const float* conv_b = (const float*)d_in[2];
    const float* rnn_w  = (const float*)d_in[3];
    const float* rnn_u  = (const float*)d_in[4];
    const float* rnn_b  = (const float*)d_in[5];
    const float* d1_w   = (const float*)d_in[6];
    const float* d1_b   = (const float*)d_in[7];
    const float* out_w  = (const float*)d_in[8];
    const float* out_b  = (const float*)d_in[9];
    float* out = (float*)d_out;

    const int B = out_size;                 // 262144
    const int grid = B / 64;                // 4096 blocks (4 waves * 16 elems)
    hybrid_fwd<<<grid, BLK, 0, stream>>>(x, conv_w, conv_b, rnn_w, rnn_u, rnn_b,
                                         d1_w, d1_b, out_w, out_b, out);
}

// Round 9
// 46.994 us; speedup vs baseline: 86.7120x; 1.1109x over previous
//
#include <hip/hip_runtime.h>

// SimpleHybridModel via MFMA, all-transposed chaining (no lane shuffles):
//  conv1d(k=3,SAME,relu) -> SimpleRNN(16,tanh) -> dense(8,relu) -> dense(1)
//
// R9 = R8 with the cvt_pkrtz type fix (__fp16x2 union members; builtin returns
// __fp16 ext_vector, incompatible with _Float16 vectors under clang).
// R8 design notes (instruction-count attack; R7 was VALU-issue-bound):
//  - x rows padded to 8 halves (16B): window start = base + 16*(l+g) bytes ->
//    B1 = ONE aligned ds_read_b128 per iter (was 4.5 b32 + 2 alignbit).
//    Element stride 92 dwords (4*23, 23 odd -> uniform 8 lanes/bank-quad).
//  - A1 k-map = 8*tap+f (K=24 used); f=7 dummy half = 1.0, A1[31] = conv_b:
//    conv bias rides the MFMA with C=0 (no acc copies).
//  - 2*log2e folded into A2/AU/rnn_b: tanh = rcp(1+exp2(a2)), raw v_exp_f32.
//  - all f16 cvts packed (v_cvt_pkrtz): 8 -> 4 per iter.
//  - staging: row-per-thread (5 rounds x [7 dword loads, 4 pkrtz, 1
//    ds_write_b128]); zero-init only rows -1,20,21 (3 rounds).
//  - head: 4th MFMA (A=d1_w^T, C=d1_b) + 4 fma + 2 shfl_xor.

#define BLK 256   // 4 waves; each wave owns 16 batch elements
#define LSEQ 20
#define EPD 92    // dwords per element: 23 rows (r=-1..21) * 4 dwords (8 halves)
#define LOG2E2 2.8853900817779268f   // 2*log2(e)

typedef _Float16 f16;
typedef __fp16   fp16x2 __attribute__((ext_vector_type(2)));   // cvt_pkrtz result type
typedef _Float16 f16x4 __attribute__((ext_vector_type(4)));
typedef _Float16 f16x8 __attribute__((ext_vector_type(8)));
typedef float    f32x4 __attribute__((ext_vector_type(4)));

union UB128 { uint4 q; f16x8 v; };
union UB64  { f16x4 v; fp16x2 p[2]; };
union HU    { fp16x2 p; uint u; };

__global__ __launch_bounds__(BLK, 6) void hybrid_fwd(
    const float* __restrict__ x,
    const float* __restrict__ conv_w, const float* __restrict__ conv_b,
    const float* __restrict__ rnn_w,  const float* __restrict__ rnn_u,
    const float* __restrict__ rnn_b,
    const float* __restrict__ d1_w,   const float* __restrict__ d1_b,
    const float* __restrict__ out_w,  const float* __restrict__ out_b,
    float* __restrict__ out)
{
    __shared__ __align__(16) uint xs[64 * EPD];   // 23552 B

    const int tid  = threadIdx.x;
    const int wave = tid >> 6, lane = tid & 63;
    const int b16  = lane & 15, g = lane >> 4;
    const long BE  = (long)blockIdx.x * 64;

    // ---- init rows -1 (dw 0..3), 20,21 (dw 84..91); dummy half (f=7) = 1.0 ----
    #pragma unroll
    for (int k = 0; k < 3; ++k) {
        int t = tid + k * BLK;                    // 768 = 64 elems * 12 dwords
        int e = t / 12, s = t - e * 12;
        xs[e * EPD + (s < 4 ? s : 80 + s)] = ((s & 3) == 3) ? 0x3C000000u : 0u;
    }
    // ---- stage x: row-per-thread; 1280 tasks = 5 rounds ----
    const float* xg = x + BE * 140;
    #pragma unroll 2
    for (int k = 0; k < 5; ++k) {
        int t = tid + k * BLK;
        int e = t / 20, r = t - e * 20;
        const float* rp = xg + e * 140 + r * 7;
        float f0 = rp[0], f1 = rp[1], f2 = rp[2], f3 = rp[3];
        float f4 = rp[4], f5 = rp[5], f6 = rp[6];
        HU h0, h1, h2, h3;
        h0.p = __builtin_amdgcn_cvt_pkrtz(f0, f1);
        h1.p = __builtin_amdgcn_cvt_pkrtz(f2, f3);
        h2.p = __builtin_amdgcn_cvt_pkrtz(f4, f5);
        h3.p = __builtin_amdgcn_cvt_pkrtz(f6, 1.0f);   // f7 dummy = 1.0 (bias lane)
        uint4 val; val.x = h0.u; val.y = h1.u; val.z = h2.u; val.w = h3.u;
        *(uint4*)&xs[e * EPD + 4 * (r + 1)] = val;     // 16B aligned
    }
    __syncthreads();

    // ---- weight fragments (register-resident, loaded once) ----
    // A1[m=co=b16, k=8g+t]: g = conv tap (0..2), t = feature (0..6);
    // k==31 -> conv_b (pairs with B1's 1.0 dummy); other slots 0.
    f16x8 A1;
    #pragma unroll
    for (int t = 0; t < 8; ++t) {
        float wv = conv_w[min(g * 7 + t, 20) * 16 + b16];
        float sel = (g < 3 && t < 7) ? wv
                  : ((g == 3 && t == 7) ? conv_b[b16] : 0.f);
        A1[t] = (f16)sel;
    }
    // A2/AU/rb scaled by 2*log2(e): a2 = 2log2e*s, so e^{2s} = exp2(a2).
    f16x4 A2, AU;
    f32x4 rbp;
    #pragma unroll
    for (int t = 0; t < 4; ++t) {
        A2[t]  = (f16)(LOG2E2 * rnn_w[(4 * g + t) * 16 + b16]);
        AU[t]  = (f16)(LOG2E2 * rnn_u[(4 * g + t) * 16 + b16]);
        rbp[t] = LOG2E2 * rnn_b[4 * g + t];
    }
    const f32x4 zero4 = {0.f, 0.f, 0.f, 0.f};

    // per-lane read base: element (wave*16+b16), tap-group offset 4g dwords
    const uint* rbase = xs + (wave * 16 + b16) * EPD + 4 * g;

    f16x4 H = {};            // h_t fragment (f16), feeds AU-MFMA and head

    #pragma unroll 4
    for (int l = 0; l < LSEQ; ++l) {
        UB128 B1;
        B1.q = *(const uint4*)(rbase + 4 * l);   // rows l-1+g, one b128
        f32x4 a1 = __builtin_amdgcn_mfma_f32_16x16x32_f16(A1, B1.v, zero4, 0, 0, 0);
        UB64 B2;                                  // relu + packed cvt
        B2.p[0] = __builtin_amdgcn_cvt_pkrtz(fmaxf(a1[0], 0.f), fmaxf(a1[1], 0.f));
        B2.p[1] = __builtin_amdgcn_cvt_pkrtz(fmaxf(a1[2], 0.f), fmaxf(a1[3], 0.f));
        f32x4 a2 = __builtin_amdgcn_mfma_f32_16x16x16f16(A2, B2.v, rbp, 0, 0, 0);
        a2 = __builtin_amdgcn_mfma_f32_16x16x16f16(AU, H, a2, 0, 0, 0);
        // tanh(s) = 1 - 2*rcp(1 + exp2(a2));  a2 = 2log2e*s
        float t0 = __builtin_amdgcn_rcpf(1.f + __builtin_amdgcn_exp2f(a2[0]));
        float t1 = __builtin_amdgcn_rcpf(1.f + __builtin_amdgcn_exp2f(a2[1]));
        float t2 = __builtin_amdgcn_rcpf(1.f + __builtin_amdgcn_exp2f(a2[2]));
        float t3 = __builtin_amdgcn_rcpf(1.f + __builtin_amdgcn_exp2f(a2[3]));
        UB64 Hn;
        Hn.p[0] = __builtin_amdgcn_cvt_pkrtz(fmaf(-2.f, t0, 1.f), fmaf(-2.f, t1, 1.f));
        Hn.p[1] = __builtin_amdgcn_cvt_pkrtz(fmaf(-2.f, t2, 1.f), fmaf(-2.f, t3, 1.f));
        H = Hn.v;
    }

    // ---- head via MFMA: z^T[d][b] = sum_j d1_w[j][d]*H[j][b] + d1_b[d] ----
    f16x4 A3;
    f32x4 c3;
    #pragma unroll
    for (int t = 0; t < 4; ++t) {
        int j = 4 * g + t;
        A3[t] = (f16)(b16 < 8 ? d1_w[j * 8 + b16] : 0.f);
        c3[t] = d1_b[min(j, 7)];                 // rows>=8 garbage (finite)
    }
    f32x4 a3 = __builtin_amdgcn_mfma_f32_16x16x16f16(A3, H, c3, 0, 0, 0);
    float part = 0.f;
    #pragma unroll
    for (int r = 0; r < 4; ++r) {
        int d = 4 * g + r;                       // valid for g<2
        float wv = (g < 2) ? out_w[min(d, 7)] : 0.f;
        part = fmaf(fmaxf(a3[r], 0.f), wv, part);
    }
    part += __shfl_xor(part, 16);                // sum over g
    part += __shfl_xor(part, 32);
    if (lane < 16)
        out[BE + wave * 16 + lane] = part + out_b[0];
}

extern "C" void kernel_launch(void* const* d_in, const int* in_sizes, int n_in,
                              void* d_out, int out_size, void* d_ws, size_t ws_size,
                              hipStream_t stream) {
    const float* x      = (const float*)d_in[0];
    const float* conv_w = (const float*)d_in[1];
    const float* conv_b = (const float*)d_in[2];
    const float* rnn_w  = (const float*)d_in[3];
    const float* rnn_u  = (const float*)d_in[4];
    const float* rnn_b  = (const float*)d_in[5];
    const float* d1_w   = (const float*)d_in[6];
    const float* d1_b   = (const float*)d_in[7];
    const float* out_w  = (const float*)d_in[8];
    const float* out_b  = (const float*)d_in[9];
    float* out = (float*)d_out;

    const int B = out_size;                 // 262144
    const int grid = B / 64;                // 4096 blocks (4 waves * 16 elems)
    hybrid_fwd<<<grid, BLK, 0, stream>>>(x, conv_w, conv_b, rnn_w, rnn_u, rnn_b,
                                         d1_w, d1_b, out_w, out_b, out);
}